// Round 1
// baseline (158.537 us; speedup 1.0000x reference)
//
#include <hip/hip_runtime.h>

namespace {
constexpr int CBS   = 320;        // combined batch size
constexpr int R     = 64;         // rank == wave size
constexpr int K     = 4096;
constexpr int SPLIT = 4;          // k-split across blocks (occupancy)
constexpr int KS    = K / SPLIT;  // 1024 k per block
constexpr int TK    = 64;         // k-tile staged in LDS
constexpr int NT    = 256;        // 4 waves per block
constexpr int NW    = NT / 64;
constexpr int LSTRIDE = TK + 1;   // +1 pad: read bank = (r + dk) % 32 -> 2-way (free)
}

__global__ __launch_bounds__(NT)
void lora_a_kernel(const float* __restrict__ x,
                   const int*   __restrict__ xids,
                   const int*   __restrict__ wids,
                   const float* __restrict__ A,
                   float*       __restrict__ out)
{
    __shared__ float xs[R * LSTRIDE];   // 64 x 65 floats = 16.25 KiB
    __shared__ float red[NW * R];

    const int bid  = blockIdx.x;
    const int c    = bid / SPLIT;
    const int s    = bid % SPLIT;
    const int t    = threadIdx.x;
    const int wave = t >> 6;
    const int lane = t & 63;

    const int wid = wids[c];
    const float* __restrict__ Aw = A + (size_t)wid * (K * R);

    // staging role: thread t fills row (t>>2), quarter (t&3) of the x tile.
    // 4 consecutive threads cover one row -> 64B-contiguous float4 loads.
    const int rw  = t >> 2;
    const int jq  = t & 3;
    const int tok = xids[c * R + rw];
    const float* __restrict__ xrow = x + (size_t)tok * K + s * KS + jq * 16;

    float acc = 0.0f;

    for (int tile = 0; tile < KS / TK; ++tile) {
        // ---- stage x tile (64 rows x 64 k) into LDS ----
        const float4* __restrict__ src = (const float4*)(xrow + tile * TK);
        float* dst = xs + rw * LSTRIDE + jq * 16;
#pragma unroll
        for (int ii = 0; ii < 4; ++ii) {
            float4 v = src[ii];
            dst[ii * 4 + 0] = v.x;   // scalar writes: bank = (rw + 16*jq + e) % 32
            dst[ii * 4 + 1] = v.y;   // -> exactly 2 lanes/bank (free)
            dst[ii * 4 + 2] = v.z;
            dst[ii * 4 + 3] = v.w;
        }
        __syncthreads();

        // ---- compute: lane = r; wave w covers dk in [w*16, w*16+16) ----
        // A read: 64 lanes x 4B contiguous = one 256B transaction per k.
        const int k0 = s * KS + tile * TK + wave * (TK / NW);
        const float* __restrict__ Ap = Aw + (size_t)k0 * R + lane;
        const float* __restrict__ xp = xs + lane * LSTRIDE + wave * (TK / NW);
#pragma unroll
        for (int i = 0; i < TK / NW; ++i) {
            acc = fmaf(xp[i], Ap[(size_t)i * R], acc);
        }
        __syncthreads();   // xs reused next tile
    }

    // ---- reduce 4 wave-partials per r, one atomic per output element ----
    red[wave * R + lane] = acc;
    __syncthreads();
    if (wave == 0) {
        float sum = red[lane] + red[R + lane] + red[2 * R + lane] + red[3 * R + lane];
        atomicAdd(&out[c * R + lane], sum);
    }
}

extern "C" void kernel_launch(void* const* d_in, const int* in_sizes, int n_in,
                              void* d_out, int out_size, void* d_ws, size_t ws_size,
                              hipStream_t stream)
{
    (void)in_sizes; (void)n_in; (void)d_ws; (void)ws_size;
    const float* x    = (const float*)d_in[0];
    const int*   xids = (const int*)d_in[1];
    const int*   wids = (const int*)d_in[2];
    const float* A    = (const float*)d_in[3];
    float* out        = (float*)d_out;

    // d_out is poisoned to 0xAA before every launch; we accumulate atomically.
    hipMemsetAsync(out, 0, (size_t)out_size * sizeof(float), stream);

    hipLaunchKernelGGL(lora_a_kernel, dim3(CBS * SPLIT), dim3(NT), 0, stream,
                       x, xids, wids, A, out);
}

// Round 2
// 155.984 us; speedup vs baseline: 1.0164x; 1.0164x over previous
//
#include <hip/hip_runtime.h>

namespace {
constexpr int CBS   = 320;        // combined batch size
constexpr int R     = 64;         // rank
constexpr int K     = 4096;
constexpr int SPLIT = 8;          // k-split across blocks (occupancy: 2560 blocks)
constexpr int KS    = K / SPLIT;  // 512 k per block
constexpr int TK    = 64;         // k-tile staged in LDS
constexpr int NT    = 256;        // 4 waves per block
constexpr int NW    = NT / 64;
constexpr int NTILES = KS / TK;   // 8
}

__global__ __launch_bounds__(NT)
void lora_a_kernel(const float* __restrict__ x,
                   const int*   __restrict__ xids,
                   const int*   __restrict__ wids,
                   const float* __restrict__ A,
                   float*       __restrict__ out)
{
    // x tile in [k][r] layout, stride 64 (no pad): compute read is ds_read_b128,
    // which at full wave width is LDS-volume-bound (8 cyc) -> padding irrelevant.
    __shared__ float xs[TK * R];       // 16 KiB
    __shared__ float red[NW * R];      // 1 KiB

    const int bid  = blockIdx.x;
    const int c    = bid >> 3;         // combo
    const int s    = bid & 7;          // k-split slice
    const int t    = threadIdx.x;
    const int wave = t >> 6;
    const int lane = t & 63;
    const int r4   = lane & 15;        // r group: this lane owns r = 4*r4 .. 4*r4+3
    const int kq   = lane >> 4;        // k interleave within wave

    const int wid = wids[c];
    const float* __restrict__ Aw = A + (size_t)wid * (K * R);

    // staging role: thread t loads row (t>>2), k-quarter (t&3): 4 float4,
    // 64B contiguous per row group -> coalesced.
    const int rw  = t >> 2;
    const int jq  = t & 3;
    const int tok = xids[c * R + rw];
    const float* __restrict__ xrow = x + (size_t)tok * K + s * KS + jq * 16;

    float4 acc = make_float4(0.f, 0.f, 0.f, 0.f);

    // prefetch tile 0
    float4 pv[4];
    {
        const float4* src = (const float4*)xrow;
#pragma unroll
        for (int ii = 0; ii < 4; ++ii) pv[ii] = src[ii];
    }

    for (int tile = 0; tile < NTILES; ++tile) {
        // ---- write prefetched x tile into LDS ([k][r] scatter, scalar) ----
#pragma unroll
        for (int ii = 0; ii < 4; ++ii) {
            const int kk = jq * 16 + ii * 4;
            xs[(kk + 0) * R + rw] = pv[ii].x;
            xs[(kk + 1) * R + rw] = pv[ii].y;
            xs[(kk + 2) * R + rw] = pv[ii].z;
            xs[(kk + 3) * R + rw] = pv[ii].w;
        }
        __syncthreads();

        // ---- prefetch next tile while computing this one ----
        if (tile + 1 < NTILES) {
            const float4* src = (const float4*)(xrow + (tile + 1) * TK);
#pragma unroll
            for (int ii = 0; ii < 4; ++ii) pv[ii] = src[ii];
        }

        // ---- compute: wave covers k-rows [w*16, w*16+16) of the tile ----
        // instr i: 64 lanes read A rows (kw + kq + 4i), 16B/lane -> 1KiB contiguous
        const int kw = wave * 16 + kq;                       // local k base
        const float* __restrict__ Ap =
            Aw + (size_t)(s * KS + tile * TK + kw) * R + 4 * r4;
#pragma unroll
        for (int i = 0; i < 4; ++i) {
            float4 av = *(const float4*)(Ap + (size_t)(4 * i) * R);
            float4 xv = *(const float4*)(&xs[(kw + 4 * i) * R + 4 * r4]);
            acc.x = fmaf(xv.x, av.x, acc.x);
            acc.y = fmaf(xv.y, av.y, acc.y);
            acc.z = fmaf(xv.z, av.z, acc.z);
            acc.w = fmaf(xv.w, av.w, acc.w);
        }
        __syncthreads();   // xs reused next tile
    }

    // ---- reduce over kq (lanes r4, r4+16, r4+32, r4+48) via shuffles ----
#pragma unroll
    for (int m = 16; m < 64; m <<= 1) {
        acc.x += __shfl_xor(acc.x, m, 64);
        acc.y += __shfl_xor(acc.y, m, 64);
        acc.z += __shfl_xor(acc.z, m, 64);
        acc.w += __shfl_xor(acc.w, m, 64);
    }
    if (kq == 0) {
        float* rd = &red[wave * R + 4 * r4];
        rd[0] = acc.x; rd[1] = acc.y; rd[2] = acc.z; rd[3] = acc.w;
    }
    __syncthreads();

    // ---- one atomic per output element (8 blocks contribute per element) ----
    if (wave == 0) {
        float sum = red[lane] + red[R + lane] + red[2 * R + lane] + red[3 * R + lane];
        atomicAdd(&out[c * R + lane], sum);
    }
}

extern "C" void kernel_launch(void* const* d_in, const int* in_sizes, int n_in,
                              void* d_out, int out_size, void* d_ws, size_t ws_size,
                              hipStream_t stream)
{
    (void)in_sizes; (void)n_in; (void)d_ws; (void)ws_size;
    const float* x    = (const float*)d_in[0];
    const int*   xids = (const int*)d_in[1];
    const int*   wids = (const int*)d_in[2];
    const float* A    = (const float*)d_in[3];
    float* out        = (float*)d_out;

    // d_out is poisoned to 0xAA before every launch; we accumulate atomically.
    hipMemsetAsync(out, 0, (size_t)out_size * sizeof(float), stream);

    hipLaunchKernelGGL(lora_a_kernel, dim3(CBS * SPLIT), dim3(NT), 0, stream,
                       x, xids, wids, A, out);
}

// Round 3
// 147.669 us; speedup vs baseline: 1.0736x; 1.0563x over previous
//
#include <hip/hip_runtime.h>
#include <stdint.h>

namespace {
constexpr int BATCH  = 512;
constexpr int CBS    = 320;       // combined batch size
constexpr int R      = 64;        // rank
constexpr int K      = 4096;
constexpr int NADAPT = 80;
constexpr int SPLIT  = 8;         // k-split across blocks
constexpr int KS     = K / SPLIT; // 512 k per block
constexpr int TK     = 64;        // k-tile staged in LDS
constexpr int NT     = 256;       // 4 waves
constexpr int NW     = NT / 64;
constexpr int NTILES = KS / TK;   // 8

// ws layout: perm[320] ints at 0; x_bf16[512][4096] at byte 4096
constexpr size_t WS_X_OFF  = 4096;
constexpr size_t WS_NEEDED = WS_X_OFF + (size_t)BATCH * K * 2;  // ~4.2 MiB

__device__ inline uint16_t f2bf(float f) {   // RNE fp32 -> bf16
    uint32_t u = __float_as_uint(f);
    u += 0x7fffu + ((u >> 16) & 1u);
    return (uint16_t)(u >> 16);
}
__device__ inline float bf2f(uint16_t b) {
    return __uint_as_float((uint32_t)b << 16);
}
}

// ---- pre-pass 1: wid-sorted permutation of combo indices ----
__global__ void sort_by_wid(const int* __restrict__ wids, int* __restrict__ perm)
{
    __shared__ int hist[NADAPT];
    __shared__ int offs[NADAPT];
    const int t = threadIdx.x;
    if (t < NADAPT) hist[t] = 0;
    __syncthreads();
    atomicAdd(&hist[wids[t]], 1);        // t in [0,320)
    __syncthreads();
    if (t == 0) {
        int run = 0;
        for (int i = 0; i < NADAPT; ++i) { offs[i] = run; run += hist[i]; }
    }
    __syncthreads();
    const int pos = atomicAdd(&offs[wids[t]], 1);
    perm[pos] = t;
}

// ---- pre-pass 2: x fp32 -> bf16 into ws (halves x working set: L2-resident) ----
__global__ __launch_bounds__(256)
void cvt_x(const float* __restrict__ x, uint16_t* __restrict__ xb)
{
    const int i = blockIdx.x * 256 + threadIdx.x;   // over BATCH*K/4 float4s
    const float4 v = ((const float4*)x)[i];
    ushort4 o;
    o.x = f2bf(v.x); o.y = f2bf(v.y); o.z = f2bf(v.z); o.w = f2bf(v.w);
    ((ushort4*)xb)[i] = o;
}

// ---- main: block (i,s) handles combo perm[i], k-slice s ----
__global__ __launch_bounds__(NT)
void lora_main(const int* __restrict__ xids,
               const int* __restrict__ wids,
               const float* __restrict__ A,
               const uint16_t* __restrict__ xb,
               const int* __restrict__ perm,
               float* __restrict__ out)
{
    // xs: [k][r'] fp32, r' = r ^ ((k>>4)*16). Swizzle makes staging writes
    // 2-way bank (free) and keeps compute float4 reads 4-aligned-contiguous.
    __shared__ float xs[TK * R];       // 16 KiB
    __shared__ float red[NW * R];

    const int bid  = blockIdx.x;
    const int i0   = bid >> 3;         // sorted combo index (same-wid adjacent)
    const int s    = bid & 7;          // k-slice -> XCD (same-wid same-XCD)
    const int c    = perm[i0];
    const int t    = threadIdx.x;
    const int wave = t >> 6;
    const int lane = t & 63;
    const int r4   = lane & 15;        // lane owns logical r = 4*r4 .. +3
    const int kq   = lane >> 4;

    const int wid = wids[c];
    const float* __restrict__ Aw = A + (size_t)wid * (K * R);

    // staging role: thread t covers row rw = t>>2, k-chunk jq = t&3 (16 k's)
    const int rw  = t >> 2;
    const int jq  = t & 3;
    const int tok = xids[c * R + rw];
    const uint16_t* __restrict__ xrow = xb + (size_t)tok * K + s * KS + jq * 16;
    const int rsw = rw ^ (jq * 16);    // swizzled r slot for this thread's writes

    float4 acc = make_float4(0.f, 0.f, 0.f, 0.f);

    // prefetch tile 0: 16 bf16 = 2 x uint4
    uint4 p0, p1;
    {
        const uint4* src = (const uint4*)xrow;
        p0 = src[0]; p1 = src[1];
    }

    for (int tile = 0; tile < NTILES; ++tile) {
        // ---- unpack prefetched bf16 -> fp32, write swizzled LDS tile ----
        {
            const uint32_t w[8] = {p0.x, p0.y, p0.z, p0.w, p1.x, p1.y, p1.z, p1.w};
            float* base = xs + (jq * 16) * R + rsw;
#pragma unroll
            for (int m = 0; m < 8; ++m) {
                base[(2 * m + 0) * R] = bf2f((uint16_t)(w[m] & 0xffffu));
                base[(2 * m + 1) * R] = bf2f((uint16_t)(w[m] >> 16));
            }
        }
        __syncthreads();

        // ---- prefetch next tile across the compute phase ----
        if (tile + 1 < NTILES) {
            const uint4* src = (const uint4*)(xrow + (tile + 1) * TK);
            p0 = src[0]; p1 = src[1];
        }

        // ---- compute: wave covers tile-local k in [wave*16, wave*16+16) ----
        const int kw = wave * 16 + kq;
        const int rr = (4 * r4) ^ (wave * 16);   // swizzled read slot
        const float* __restrict__ Ap =
            Aw + (size_t)(s * KS + tile * TK + kw) * R + 4 * r4;
#pragma unroll
        for (int i = 0; i < 4; ++i) {
            float4 av = *(const float4*)(Ap + (size_t)(4 * i) * R);
            float4 xv = *(const float4*)(&xs[(kw + 4 * i) * R + rr]);
            acc.x = fmaf(xv.x, av.x, acc.x);
            acc.y = fmaf(xv.y, av.y, acc.y);
            acc.z = fmaf(xv.z, av.z, acc.z);
            acc.w = fmaf(xv.w, av.w, acc.w);
        }
        __syncthreads();
    }

    // ---- reduce over kq, then waves, one atomic per output element ----
#pragma unroll
    for (int m = 16; m < 64; m <<= 1) {
        acc.x += __shfl_xor(acc.x, m, 64);
        acc.y += __shfl_xor(acc.y, m, 64);
        acc.z += __shfl_xor(acc.z, m, 64);
        acc.w += __shfl_xor(acc.w, m, 64);
    }
    if (kq == 0) {
        float* rd = &red[wave * R + 4 * r4];
        rd[0] = acc.x; rd[1] = acc.y; rd[2] = acc.z; rd[3] = acc.w;
    }
    __syncthreads();
    if (wave == 0) {
        float sum = red[lane] + red[R + lane] + red[2 * R + lane] + red[3 * R + lane];
        atomicAdd(&out[c * R + lane], sum);
    }
}

// ---- fallback (ws too small): R2 kernel, fp32 x from global, no perm ----
__global__ __launch_bounds__(NT)
void lora_fallback(const float* __restrict__ x,
                   const int*   __restrict__ xids,
                   const int*   __restrict__ wids,
                   const float* __restrict__ A,
                   float*       __restrict__ out)
{
    __shared__ float xs[TK * R];
    __shared__ float red[NW * R];
    const int bid  = blockIdx.x;
    const int c    = bid >> 3;
    const int s    = bid & 7;
    const int t    = threadIdx.x;
    const int wave = t >> 6;
    const int lane = t & 63;
    const int r4   = lane & 15;
    const int kq   = lane >> 4;
    const int wid  = wids[c];
    const float* __restrict__ Aw = A + (size_t)wid * (K * R);
    const int rw  = t >> 2;
    const int jq  = t & 3;
    const int tok = xids[c * R + rw];
    const float* __restrict__ xrow = x + (size_t)tok * K + s * KS + jq * 16;
    float4 acc = make_float4(0.f, 0.f, 0.f, 0.f);
    float4 pv[4];
    {
        const float4* src = (const float4*)xrow;
#pragma unroll
        for (int ii = 0; ii < 4; ++ii) pv[ii] = src[ii];
    }
    for (int tile = 0; tile < NTILES; ++tile) {
#pragma unroll
        for (int ii = 0; ii < 4; ++ii) {
            const int kk = jq * 16 + ii * 4;
            xs[(kk + 0) * R + rw] = pv[ii].x;
            xs[(kk + 1) * R + rw] = pv[ii].y;
            xs[(kk + 2) * R + rw] = pv[ii].z;
            xs[(kk + 3) * R + rw] = pv[ii].w;
        }
        __syncthreads();
        if (tile + 1 < NTILES) {
            const float4* src = (const float4*)(xrow + (tile + 1) * TK);
#pragma unroll
            for (int ii = 0; ii < 4; ++ii) pv[ii] = src[ii];
        }
        const int kw = wave * 16 + kq;
        const float* __restrict__ Ap =
            Aw + (size_t)(s * KS + tile * TK + kw) * R + 4 * r4;
#pragma unroll
        for (int i = 0; i < 4; ++i) {
            float4 av = *(const float4*)(Ap + (size_t)(4 * i) * R);
            float4 xv = *(const float4*)(&xs[(kw + 4 * i) * R + 4 * r4]);
            acc.x = fmaf(xv.x, av.x, acc.x);
            acc.y = fmaf(xv.y, av.y, acc.y);
            acc.z = fmaf(xv.z, av.z, acc.z);
            acc.w = fmaf(xv.w, av.w, acc.w);
        }
        __syncthreads();
    }
#pragma unroll
    for (int m = 16; m < 64; m <<= 1) {
        acc.x += __shfl_xor(acc.x, m, 64);
        acc.y += __shfl_xor(acc.y, m, 64);
        acc.z += __shfl_xor(acc.z, m, 64);
        acc.w += __shfl_xor(acc.w, m, 64);
    }
    if (kq == 0) {
        float* rd = &red[wave * R + 4 * r4];
        rd[0] = acc.x; rd[1] = acc.y; rd[2] = acc.z; rd[3] = acc.w;
    }
    __syncthreads();
    if (wave == 0) {
        float sum = red[lane] + red[R + lane] + red[2 * R + lane] + red[3 * R + lane];
        atomicAdd(&out[c * R + lane], sum);
    }
}

extern "C" void kernel_launch(void* const* d_in, const int* in_sizes, int n_in,
                              void* d_out, int out_size, void* d_ws, size_t ws_size,
                              hipStream_t stream)
{
    (void)in_sizes; (void)n_in;
    const float* x    = (const float*)d_in[0];
    const int*   xids = (const int*)d_in[1];
    const int*   wids = (const int*)d_in[2];
    const float* A    = (const float*)d_in[3];
    float* out        = (float*)d_out;

    hipMemsetAsync(out, 0, (size_t)out_size * sizeof(float), stream);

    if (ws_size >= WS_NEEDED) {
        int*      perm = (int*)d_ws;
        uint16_t* xb   = (uint16_t*)((char*)d_ws + WS_X_OFF);
        hipLaunchKernelGGL(sort_by_wid, dim3(1), dim3(CBS), 0, stream, wids, perm);
        hipLaunchKernelGGL(cvt_x, dim3(BATCH * K / 4 / 256), dim3(256), 0, stream, x, xb);
        hipLaunchKernelGGL(lora_main, dim3(CBS * SPLIT), dim3(NT), 0, stream,
                           xids, wids, A, xb, perm, out);
    } else {
        hipLaunchKernelGGL(lora_fallback, dim3(CBS * SPLIT), dim3(NT), 0, stream,
                           x, xids, wids, A, out);
    }
}